// Round 14
// baseline (49.638 us; speedup 1.0000x reference)
//
#include <hip/hip_runtime.h>
#include <hip/hip_bf16.h>
#include <stdint.h>

#define D_MODEL 1024
#define D_STATE 16
#define BATCH   4
#define SEQ     2048
#define ROWS    (BATCH*SEQ)   // 8192
#define WIN     64            // FIR window; decay<=0.55 => decay^64 < 1e-16

// async global->LDS, 16B per lane. LDS dest must be linear (base + lane*16).
__device__ __forceinline__ void gload16(const void* g, void* l) {
    __builtin_amdgcn_global_load_lds(
        (const __attribute__((address_space(1))) uint32_t*)g,
        (__attribute__((address_space(3))) uint32_t*)l, 16, 0, 0);
}

// ---------------------------------------------------------------------------
// K1: blocks 0..15 -> Kbar; blocks 16..1039 -> bx projection (8 rows each).
// x staged via global_load_lds (linear LDS dest, PRE-SWIZZLED global source:
// lane tid fetches global quad chunk*8+((slot-chunk)&7) so the swizzled
// compute-read pattern is unchanged — rule 21 both-sides-or-neither).
// ---------------------------------------------------------------------------
#define K1_ROWS 8
__global__ __launch_bounds__(256, 4) void k_proj(const float* __restrict__ x,
                                                 const float* __restrict__ Bw,
                                                 const float* __restrict__ A_log,
                                                 float* __restrict__ bx,
                                                 float* __restrict__ KbarT) {
    __shared__ float xs[K1_ROWS][1024];               // 32 KB (aliased by kbar path)
    __shared__ float red[4][8][K1_ROWS][2];           // [wave][np][row][q]
    const int tid = threadIdx.x;

    if (blockIdx.x < D_STATE) {
        // ---- Kbar path (16 blocks, first in dispatch order) ----
        const int n = blockIdx.x;
        float* l2   = &xs[0][0];                      // 1024 floats
        float* kred = &xs[1][0];                      // 4*64 floats
        const int delta = tid & 63;
        const int c     = tid >> 6;
        for (int d = tid; d < D_MODEL; d += 256) {
            float a = A_log[d * D_STATE + n];
            l2[d] = -expf(a) * 1.4426950408889634f;   // log2(decay)
        }
        __syncthreads();
        const float fdelta = (float)delta;
        float acc = 0.f;
        const int d0 = c * 256;
        for (int d = d0; d < d0 + 256; ++d)
            acc += exp2f(fdelta * l2[d]);
        kred[c * WIN + delta] = acc;
        __syncthreads();
        if (tid < WIN)
            KbarT[tid * D_STATE + n] =
                (kred[tid] + kred[WIN + tid] + kred[2 * WIN + tid] + kred[3 * WIN + tid])
                * (1.0f / 1024.0f);
        return;
    }

    // ---- bx path ----
    const int np   = tid & 7;
    const int dblk = tid >> 3;
    const int row0 = (blockIdx.x - D_STATE) * K1_ROWS;
    const int lane = tid & 63, wid = tid >> 6;

    // (1) async x staging: LDS linear at quad index tid; global source holds
    // the quad that belongs there under the rotate swizzle.
    const int chunk = tid >> 3, slot = tid & 7;
    const int srcq  = chunk * 8 + ((slot - chunk) & 7);
#pragma unroll
    for (int r = 0; r < K1_ROWS; ++r)
        gload16(x + (size_t)(row0 + r) * 1024 + srcq * 4, &xs[r][tid * 4]);

    // (2) B_w loads fill the latency shadow (regs, compile-time indexed)
    float4 bw0[8], bw1[8];
    {
        const float4* p0 = reinterpret_cast<const float4*>(Bw + (size_t)(2 * np    ) * 1024 + dblk * 32);
        const float4* p1 = reinterpret_cast<const float4*>(Bw + (size_t)(2 * np + 1) * 1024 + dblk * 32);
#pragma unroll
        for (int j = 0; j < 8; ++j) { bw0[j] = p0[j]; bw1[j] = p1[j]; }
    }
    __syncthreads();   // drains vmcnt (gload_lds) before LDS reads

    float a0[K1_ROWS], a1[K1_ROWS];
#pragma unroll
    for (int r = 0; r < K1_ROWS; ++r) { a0[r] = 0.f; a1[r] = 0.f; }

#pragma unroll
    for (int r = 0; r < K1_ROWS; ++r) {
#pragma unroll
        for (int j = 0; j < 8; ++j) {
            const int sl = (j + dblk) & 7;
            float4 xv = *reinterpret_cast<const float4*>(&xs[r][dblk * 32 + sl * 4]);
            a0[r] = fmaf(xv.x, bw0[j].x, a0[r]); a0[r] = fmaf(xv.y, bw0[j].y, a0[r]);
            a0[r] = fmaf(xv.z, bw0[j].z, a0[r]); a0[r] = fmaf(xv.w, bw0[j].w, a0[r]);
            a1[r] = fmaf(xv.x, bw1[j].x, a1[r]); a1[r] = fmaf(xv.y, bw1[j].y, a1[r]);
            a1[r] = fmaf(xv.z, bw1[j].z, a1[r]); a1[r] = fmaf(xv.w, bw1[j].w, a1[r]);
        }
    }

#pragma unroll
    for (int r = 0; r < K1_ROWS; ++r) {
        float v0 = a0[r], v1 = a1[r];
        v0 += __shfl_xor(v0, 8);  v1 += __shfl_xor(v1, 8);
        v0 += __shfl_xor(v0, 16); v1 += __shfl_xor(v1, 16);
        v0 += __shfl_xor(v0, 32); v1 += __shfl_xor(v1, 32);
        a0[r] = v0; a1[r] = v1;
    }
    if (lane < 8) {
#pragma unroll
        for (int r = 0; r < K1_ROWS; ++r) {
            red[wid][lane][r][0] = a0[r];
            red[wid][lane][r][1] = a1[r];
        }
    }
    __syncthreads();
    if (tid < K1_ROWS * 16) {
        const int r = tid >> 4, n = tid & 15;
        float v = red[0][n >> 1][r][n & 1] + red[1][n >> 1][r][n & 1]
                + red[2][n >> 1][r][n & 1] + red[3][n >> 1][r][n & 1];
        bx[(size_t)(row0 + r) * D_STATE + n] = v;
    }
}

// ---------------------------------------------------------------------------
// K2 (fused FIR + matvec + LN): 256 thr, 8 rows/block, grid 1024.
// kb4/bwin staged via global_load_lds (linear); x as 8-deep reg prefetch.
// bwin padded to [80][4] so the second staging round is a FULL wave (no
// exec-mask subtlety); its tail global addresses clamped to ROWS-1 (quads
// beyond index 283 are never read by the FIR).
// ---------------------------------------------------------------------------
#define KO_ROWS 8
__global__ __launch_bounds__(256, 3) void k_tail(const float* __restrict__ x,
                                                 const float* __restrict__ bxg,
                                                 const float* __restrict__ KbarT,
                                                 const float* __restrict__ Cw,
                                                 const float* __restrict__ Dp,
                                                 const float* __restrict__ gamma,
                                                 const float* __restrict__ beta,
                                                 float* __restrict__ out) {
    const int tid = threadIdx.x;
    const int row0 = blockIdx.x * KO_ROWS;
    const int lane = tid & 63, wid = tid >> 6;
    __shared__ float4 bwin[80][4];                 // rows row0-63..row0+7 (+pad)
    __shared__ float4 kb4[WIN][4];                 // [delta][nq]
    __shared__ float4 hm4[KO_ROWS][4];
    __shared__ float red_s[KO_ROWS][4], red_q[KO_ROWS][4];

    // (1) x prefetch first (HBM, deepest latency) — 8 rows in flight in regs
    float4 xq[KO_ROWS];
#pragma unroll
    for (int r = 0; r < KO_ROWS; ++r)
        xq[r] = reinterpret_cast<const float4*>(x + (size_t)(row0 + r) * D_MODEL)[tid];

    // (2) async LDS staging: kb (256 quads) + bwin (284 quads, 2 rounds)
    gload16(KbarT + tid * 4, &kb4[tid >> 2][tid & 3]);
    {
        const int j0 = tid >> 2, q0 = tid & 3;
        long g0 = (long)row0 - 63 + j0; if (g0 < 0) g0 = 0;      // masked in FIR
        gload16(bxg + g0 * D_STATE + q0 * 4, &bwin[j0][q0]);
        if (tid < 64) {                                          // full wave 0
            const int f1 = tid + 256;
            const int j1 = f1 >> 2, q1 = f1 & 3;                 // j1 in [64,80)
            long g1 = (long)row0 + 1 + (j1 - 64);
            if (g1 > ROWS - 1) g1 = ROWS - 1;                    // pad quads unused
            gload16(bxg + g1 * D_STATE + q1 * 4, &bwin[j1][q1]);
        }
    }
    __syncthreads();   // drains vmcnt for gload_lds (xq waits folded in too)

    // ---- FIR: tid = r*32 + dc*4 + nq ----
    {
        const int r_f = tid >> 5, dc = (tid >> 2) & 7, nq = tid & 3;
        const int t0 = row0 & (SEQ - 1);
        float4 acc = {0.f, 0.f, 0.f, 0.f};
        if (t0 >= WIN) {                           // full window for all 8 rows
#pragma unroll
            for (int j = 0; j < 8; ++j) {
                const int delta = dc * 8 + j;
                const float4 b = bwin[63 + r_f - delta][nq];
                const float4 k = kb4[delta][nq];
                acc.x = fmaf(k.x, b.x, acc.x); acc.y = fmaf(k.y, b.y, acc.y);
                acc.z = fmaf(k.z, b.z, acc.z); acc.w = fmaf(k.w, b.w, acc.w);
            }
        } else {                                   // warm-up rows: mask taps
            const int t = t0 + r_f;
#pragma unroll
            for (int j = 0; j < 8; ++j) {
                const int delta = dc * 8 + j;
                if (delta <= t) {
                    const float4 b = bwin[63 + r_f - delta][nq];
                    const float4 k = kb4[delta][nq];
                    acc.x = fmaf(k.x, b.x, acc.x); acc.y = fmaf(k.y, b.y, acc.y);
                    acc.z = fmaf(k.z, b.z, acc.z); acc.w = fmaf(k.w, b.w, acc.w);
                }
            }
        }
#pragma unroll
        for (int off = 4; off <= 16; off <<= 1) {
            acc.x += __shfl_xor(acc.x, off);
            acc.y += __shfl_xor(acc.y, off);
            acc.z += __shfl_xor(acc.z, off);
            acc.w += __shfl_xor(acc.w, off);
        }
        if (dc == 0) hm4[r_f][nq] = acc;
    }
    __syncthreads();

    // ---- matvec + D*x + LN partials: all 8 rows, one barrier ----
    float4 cw[4][4];
#pragma unroll
    for (int j = 0; j < 4; ++j) {
        const float4* p = reinterpret_cast<const float4*>(Cw + (size_t)(tid * 4 + j) * D_STATE);
#pragma unroll
        for (int q = 0; q < 4; ++q) cw[j][q] = p[q];
    }
    const float4 Dq = reinterpret_cast<const float4*>(Dp)[tid];
    const float4 gq = reinterpret_cast<const float4*>(gamma)[tid];
    const float4 bq = reinterpret_cast<const float4*>(beta)[tid];

    float4 y[KO_ROWS];
#pragma unroll
    for (int r = 0; r < KO_ROWS; ++r) {
        const float4 h0 = hm4[r][0], h1 = hm4[r][1], h2 = hm4[r][2], h3 = hm4[r][3];
        float4 v;
#pragma unroll
        for (int j = 0; j < 4; ++j) {
            float a = 0.f;
            a = fmaf(h0.x, cw[j][0].x, a); a = fmaf(h0.y, cw[j][0].y, a);
            a = fmaf(h0.z, cw[j][0].z, a); a = fmaf(h0.w, cw[j][0].w, a);
            a = fmaf(h1.x, cw[j][1].x, a); a = fmaf(h1.y, cw[j][1].y, a);
            a = fmaf(h1.z, cw[j][1].z, a); a = fmaf(h1.w, cw[j][1].w, a);
            a = fmaf(h2.x, cw[j][2].x, a); a = fmaf(h2.y, cw[j][2].y, a);
            a = fmaf(h2.z, cw[j][2].z, a); a = fmaf(h2.w, cw[j][2].w, a);
            a = fmaf(h3.x, cw[j][3].x, a); a = fmaf(h3.y, cw[j][3].y, a);
            a = fmaf(h3.z, cw[j][3].z, a); a = fmaf(h3.w, cw[j][3].w, a);
            ((float*)&v)[j] = a;
        }
        v.x = fmaf(Dq.x, xq[r].x, v.x);
        v.y = fmaf(Dq.y, xq[r].y, v.y);
        v.z = fmaf(Dq.z, xq[r].z, v.z);
        v.w = fmaf(Dq.w, xq[r].w, v.w);
        y[r] = v;

        float s  = v.x + v.y + v.z + v.w;
        float sq = v.x*v.x + v.y*v.y + v.z*v.z + v.w*v.w;
        s += __shfl_xor(s, 1);  sq += __shfl_xor(sq, 1);
        s += __shfl_xor(s, 2);  sq += __shfl_xor(sq, 2);
        s += __shfl_xor(s, 4);  sq += __shfl_xor(sq, 4);
        s += __shfl_xor(s, 8);  sq += __shfl_xor(sq, 8);
        s += __shfl_xor(s, 16); sq += __shfl_xor(sq, 16);
        s += __shfl_xor(s, 32); sq += __shfl_xor(sq, 32);
        if (lane == 0) { red_s[r][wid] = s; red_q[r][wid] = sq; }
    }
    __syncthreads();

#pragma unroll
    for (int r = 0; r < KO_ROWS; ++r) {
        const size_t row = row0 + r;
        const float ssum = red_s[r][0] + red_s[r][1] + red_s[r][2] + red_s[r][3];
        const float ssq  = red_q[r][0] + red_q[r][1] + red_q[r][2] + red_q[r][3];
        const float mu   = ssum * (1.0f / 1024.0f);
        const float var  = ssq * (1.0f / 1024.0f) - mu * mu;
        const float inv  = rsqrtf(var + 1e-5f);
        const float4 v = y[r];
        float4 o;
        o.x = fmaf((v.x - mu) * inv, gq.x, bq.x);
        o.y = fmaf((v.y - mu) * inv, gq.y, bq.y);
        o.z = fmaf((v.z - mu) * inv, gq.z, bq.z);
        o.w = fmaf((v.w - mu) * inv, gq.w, bq.w);
        reinterpret_cast<float4*>(out + row * D_MODEL)[tid] = o;
    }
}

extern "C" void kernel_launch(void* const* d_in, const int* in_sizes, int n_in,
                              void* d_out, int out_size, void* d_ws, size_t ws_size,
                              hipStream_t stream) {
    (void)in_sizes; (void)n_in; (void)out_size; (void)ws_size;
    const float* x     = (const float*)d_in[0];
    const float* A_log = (const float*)d_in[1];
    const float* B_w   = (const float*)d_in[2];
    const float* C_w   = (const float*)d_in[3];
    const float* Dp    = (const float*)d_in[4];
    const float* gamma = (const float*)d_in[5];
    const float* beta  = (const float*)d_in[6];
    float* out = (float*)d_out;

    float* bx = (float*)d_ws;                       // ROWS*16 floats (512 KB)
    float* kb = bx + (size_t)ROWS * D_STATE;        // WIN*16 floats (4 KB)

    k_proj<<<ROWS / K1_ROWS + D_STATE, 256, 0, stream>>>(x, B_w, A_log, bx, kb);
    k_tail<<<ROWS / KO_ROWS,           256, 0, stream>>>(x, bx, kb, C_w, Dp, gamma, beta, out);
}

// Round 15
// 47.847 us; speedup vs baseline: 1.0374x; 1.0374x over previous
//
#include <hip/hip_runtime.h>
#include <hip/hip_bf16.h>

#define D_MODEL 1024
#define D_STATE 16
#define BATCH   4
#define SEQ     2048
#define ROWS    (BATCH*SEQ)   // 8192
#define WIN     64            // FIR window; decay<=0.55 => decay^64 < 1e-16

// ---------------------------------------------------------------------------
// K1: blocks 0..15 -> Kbar; blocks 16..1039 -> bx projection (8 rows each).
// R12 core + async-STAGE split: all global loads (x rows, B_w slices) issued
// into registers BEFORE any LDS write — one latency drain, not eight.
// ---------------------------------------------------------------------------
#define K1_ROWS 8
__global__ __launch_bounds__(256, 4) void k_proj(const float* __restrict__ x,
                                                 const float* __restrict__ Bw,
                                                 const float* __restrict__ A_log,
                                                 float* __restrict__ bx,
                                                 float* __restrict__ KbarT) {
    __shared__ float xs[K1_ROWS][1024];               // 32 KB (aliased by kbar path)
    __shared__ float red[4][8][K1_ROWS][2];           // [wave][np][row][q]
    const int tid = threadIdx.x;

    if (blockIdx.x < D_STATE) {
        // ---- Kbar path (16 blocks, first in dispatch order) ----
        const int n = blockIdx.x;
        float* l2   = &xs[0][0];                      // 1024 floats
        float* kred = &xs[1][0];                      // 4*64 floats
        const int delta = tid & 63;
        const int c     = tid >> 6;
        for (int d = tid; d < D_MODEL; d += 256) {
            float a = A_log[d * D_STATE + n];
            l2[d] = -expf(a) * 1.4426950408889634f;   // log2(decay)
        }
        __syncthreads();
        const float fdelta = (float)delta;
        float acc = 0.f;
        const int d0 = c * 256;
        for (int d = d0; d < d0 + 256; ++d)
            acc += exp2f(fdelta * l2[d]);
        kred[c * WIN + delta] = acc;
        __syncthreads();
        if (tid < WIN)
            KbarT[tid * D_STATE + n] =
                (kred[tid] + kred[WIN + tid] + kred[2 * WIN + tid] + kred[3 * WIN + tid])
                * (1.0f / 1024.0f);
        return;
    }

    // ---- bx path ----
    const int np   = tid & 7;
    const int dblk = tid >> 3;
    const int row0 = (blockIdx.x - D_STATE) * K1_ROWS;
    const int lane = tid & 63, wid = tid >> 6;

    // (1) issue ALL x loads first (deepest latency), into regs
    float4 xr[K1_ROWS];
#pragma unroll
    for (int r = 0; r < K1_ROWS; ++r)
        xr[r] = reinterpret_cast<const float4*>(x + (size_t)(row0 + r) * 1024)[tid];

    // (2) B_w loads fill the x-latency shadow
    float4 bw0[8], bw1[8];
    {
        const float4* p0 = reinterpret_cast<const float4*>(Bw + (size_t)(2 * np    ) * 1024 + dblk * 32);
        const float4* p1 = reinterpret_cast<const float4*>(Bw + (size_t)(2 * np + 1) * 1024 + dblk * 32);
#pragma unroll
        for (int j = 0; j < 8; ++j) { bw0[j] = p0[j]; bw1[j] = p1[j]; }
    }

    // (3) LDS writes (swizzled), one drain
    const int chunk = tid >> 3;
    const int slotw = ((tid & 7) + chunk) & 7;
#pragma unroll
    for (int r = 0; r < K1_ROWS; ++r)
        *reinterpret_cast<float4*>(&xs[r][chunk * 32 + slotw * 4]) = xr[r];
    __syncthreads();

    float a0[K1_ROWS], a1[K1_ROWS];
#pragma unroll
    for (int r = 0; r < K1_ROWS; ++r) { a0[r] = 0.f; a1[r] = 0.f; }

#pragma unroll
    for (int r = 0; r < K1_ROWS; ++r) {
#pragma unroll
        for (int j = 0; j < 8; ++j) {
            const int slot = (j + dblk) & 7;
            float4 xv = *reinterpret_cast<const float4*>(&xs[r][dblk * 32 + slot * 4]);
            a0[r] = fmaf(xv.x, bw0[j].x, a0[r]); a0[r] = fmaf(xv.y, bw0[j].y, a0[r]);
            a0[r] = fmaf(xv.z, bw0[j].z, a0[r]); a0[r] = fmaf(xv.w, bw0[j].w, a0[r]);
            a1[r] = fmaf(xv.x, bw1[j].x, a1[r]); a1[r] = fmaf(xv.y, bw1[j].y, a1[r]);
            a1[r] = fmaf(xv.z, bw1[j].z, a1[r]); a1[r] = fmaf(xv.w, bw1[j].w, a1[r]);
        }
    }

#pragma unroll
    for (int r = 0; r < K1_ROWS; ++r) {
        float v0 = a0[r], v1 = a1[r];
        v0 += __shfl_xor(v0, 8);  v1 += __shfl_xor(v1, 8);
        v0 += __shfl_xor(v0, 16); v1 += __shfl_xor(v1, 16);
        v0 += __shfl_xor(v0, 32); v1 += __shfl_xor(v1, 32);
        a0[r] = v0; a1[r] = v1;
    }
    if (lane < 8) {
#pragma unroll
        for (int r = 0; r < K1_ROWS; ++r) {
            red[wid][lane][r][0] = a0[r];
            red[wid][lane][r][1] = a1[r];
        }
    }
    __syncthreads();
    if (tid < K1_ROWS * 16) {
        const int r = tid >> 4, n = tid & 15;
        float v = red[0][n >> 1][r][n & 1] + red[1][n >> 1][r][n & 1]
                + red[2][n >> 1][r][n & 1] + red[3][n >> 1][r][n & 1];
        bx[(size_t)(row0 + r) * D_STATE + n] = v;
    }
}

// ---------------------------------------------------------------------------
// K2 (fused FIR + matvec + LN): 256 thr, 8 rows/block, grid 1024.
// R12 core + async-STAGE split on kb/bwin staging (loads to regs, then LDS).
// ---------------------------------------------------------------------------
#define KO_ROWS 8
__global__ __launch_bounds__(256, 3) void k_tail(const float* __restrict__ x,
                                                 const float* __restrict__ bxg,
                                                 const float* __restrict__ KbarT,
                                                 const float* __restrict__ Cw,
                                                 const float* __restrict__ Dp,
                                                 const float* __restrict__ gamma,
                                                 const float* __restrict__ beta,
                                                 float* __restrict__ out) {
    const int tid = threadIdx.x;
    const int row0 = blockIdx.x * KO_ROWS;
    const int lane = tid & 63, wid = tid >> 6;
    __shared__ float4 bwin[71][4];                 // rows row0-63 .. row0+7
    __shared__ float4 kb4[WIN][4];                 // [delta][nq]
    __shared__ float4 hm4[KO_ROWS][4];
    __shared__ float red_s[KO_ROWS][4], red_q[KO_ROWS][4];

    // (1) x prefetch first (HBM, deepest latency) — 8 rows in flight
    float4 xq[KO_ROWS];
#pragma unroll
    for (int r = 0; r < KO_ROWS; ++r)
        xq[r] = reinterpret_cast<const float4*>(x + (size_t)(row0 + r) * D_MODEL)[tid];

    // (2) kb + bwin loads into regs (L2-resident)
    const float4 kbv = reinterpret_cast<const float4*>(KbarT)[tid];
    const float4* bx4 = reinterpret_cast<const float4*>(bxg);
    const int j0 = tid >> 2, q0 = tid & 3;
    long g0 = (long)row0 - 63 + j0; if (g0 < 0) g0 = 0;
    const float4 bv0 = bx4[g0 * 4 + q0];
    float4 bv1 = {0.f, 0.f, 0.f, 0.f};
    const int f1 = tid + 256;                      // covers indices 256..283
    if (tid < 71 * 4 - 256) {
        const int j1 = f1 >> 2, q1 = f1 & 3;
        long g1 = (long)row0 - 63 + j1; if (g1 < 0) g1 = 0;
        bv1 = bx4[g1 * 4 + q1];
    }

    // (3) LDS writes
    kb4[tid >> 2][tid & 3] = kbv;
    bwin[j0][q0] = bv0;
    if (tid < 71 * 4 - 256) bwin[f1 >> 2][f1 & 3] = bv1;
    __syncthreads();

    // ---- FIR: tid = r*32 + dc*4 + nq ----
    {
        const int r_f = tid >> 5, dc = (tid >> 2) & 7, nq = tid & 3;
        const int t0 = row0 & (SEQ - 1);
        float4 acc = {0.f, 0.f, 0.f, 0.f};
        if (t0 >= WIN) {                           // full window for all 8 rows
#pragma unroll
            for (int j = 0; j < 8; ++j) {
                const int delta = dc * 8 + j;
                const float4 b = bwin[63 + r_f - delta][nq];
                const float4 k = kb4[delta][nq];
                acc.x = fmaf(k.x, b.x, acc.x); acc.y = fmaf(k.y, b.y, acc.y);
                acc.z = fmaf(k.z, b.z, acc.z); acc.w = fmaf(k.w, b.w, acc.w);
            }
        } else {                                   // warm-up rows: mask taps
            const int t = t0 + r_f;
#pragma unroll
            for (int j = 0; j < 8; ++j) {
                const int delta = dc * 8 + j;
                if (delta <= t) {
                    const float4 b = bwin[63 + r_f - delta][nq];
                    const float4 k = kb4[delta][nq];
                    acc.x = fmaf(k.x, b.x, acc.x); acc.y = fmaf(k.y, b.y, acc.y);
                    acc.z = fmaf(k.z, b.z, acc.z); acc.w = fmaf(k.w, b.w, acc.w);
                }
            }
        }
#pragma unroll
        for (int off = 4; off <= 16; off <<= 1) {
            acc.x += __shfl_xor(acc.x, off);
            acc.y += __shfl_xor(acc.y, off);
            acc.z += __shfl_xor(acc.z, off);
            acc.w += __shfl_xor(acc.w, off);
        }
        if (dc == 0) hm4[r_f][nq] = acc;
    }
    __syncthreads();

    // ---- matvec + D*x + LN partials: all 8 rows, no intermediate barrier ----
    float4 cw[4][4];
#pragma unroll
    for (int j = 0; j < 4; ++j) {
        const float4* p = reinterpret_cast<const float4*>(Cw + (size_t)(tid * 4 + j) * D_STATE);
#pragma unroll
        for (int q = 0; q < 4; ++q) cw[j][q] = p[q];
    }
    const float4 Dq = reinterpret_cast<const float4*>(Dp)[tid];
    const float4 gq = reinterpret_cast<const float4*>(gamma)[tid];
    const float4 bq = reinterpret_cast<const float4*>(beta)[tid];

    float4 y[KO_ROWS];
#pragma unroll
    for (int r = 0; r < KO_ROWS; ++r) {
        const float4 h0 = hm4[r][0], h1 = hm4[r][1], h2 = hm4[r][2], h3 = hm4[r][3];
        float4 v;
#pragma unroll
        for (int j = 0; j < 4; ++j) {
            float a = 0.f;
            a = fmaf(h0.x, cw[j][0].x, a); a = fmaf(h0.y, cw[j][0].y, a);
            a = fmaf(h0.z, cw[j][0].z, a); a = fmaf(h0.w, cw[j][0].w, a);
            a = fmaf(h1.x, cw[j][1].x, a); a = fmaf(h1.y, cw[j][1].y, a);
            a = fmaf(h1.z, cw[j][1].z, a); a = fmaf(h1.w, cw[j][1].w, a);
            a = fmaf(h2.x, cw[j][2].x, a); a = fmaf(h2.y, cw[j][2].y, a);
            a = fmaf(h2.z, cw[j][2].z, a); a = fmaf(h2.w, cw[j][2].w, a);
            a = fmaf(h3.x, cw[j][3].x, a); a = fmaf(h3.y, cw[j][3].y, a);
            a = fmaf(h3.z, cw[j][3].z, a); a = fmaf(h3.w, cw[j][3].w, a);
            ((float*)&v)[j] = a;
        }
        v.x = fmaf(Dq.x, xq[r].x, v.x);
        v.y = fmaf(Dq.y, xq[r].y, v.y);
        v.z = fmaf(Dq.z, xq[r].z, v.z);
        v.w = fmaf(Dq.w, xq[r].w, v.w);
        y[r] = v;

        float s  = v.x + v.y + v.z + v.w;
        float sq = v.x*v.x + v.y*v.y + v.z*v.z + v.w*v.w;
        s += __shfl_xor(s, 1);  sq += __shfl_xor(sq, 1);
        s += __shfl_xor(s, 2);  sq += __shfl_xor(sq, 2);
        s += __shfl_xor(s, 4);  sq += __shfl_xor(sq, 4);
        s += __shfl_xor(s, 8);  sq += __shfl_xor(sq, 8);
        s += __shfl_xor(s, 16); sq += __shfl_xor(sq, 16);
        s += __shfl_xor(s, 32); sq += __shfl_xor(sq, 32);
        if (lane == 0) { red_s[r][wid] = s; red_q[r][wid] = sq; }
    }
    __syncthreads();

#pragma unroll
    for (int r = 0; r < KO_ROWS; ++r) {
        const size_t row = row0 + r;
        const float ssum = red_s[r][0] + red_s[r][1] + red_s[r][2] + red_s[r][3];
        const float ssq  = red_q[r][0] + red_q[r][1] + red_q[r][2] + red_q[r][3];
        const float mu   = ssum * (1.0f / 1024.0f);
        const float var  = ssq * (1.0f / 1024.0f) - mu * mu;
        const float inv  = rsqrtf(var + 1e-5f);
        const float4 v = y[r];
        float4 o;
        o.x = fmaf((v.x - mu) * inv, gq.x, bq.x);
        o.y = fmaf((v.y - mu) * inv, gq.y, bq.y);
        o.z = fmaf((v.z - mu) * inv, gq.z, bq.z);
        o.w = fmaf((v.w - mu) * inv, gq.w, bq.w);
        reinterpret_cast<float4*>(out + row * D_MODEL)[tid] = o;
    }
}

extern "C" void kernel_launch(void* const* d_in, const int* in_sizes, int n_in,
                              void* d_out, int out_size, void* d_ws, size_t ws_size,
                              hipStream_t stream) {
    (void)in_sizes; (void)n_in; (void)out_size; (void)ws_size;
    const float* x     = (const float*)d_in[0];
    const float* A_log = (const float*)d_in[1];
    const float* B_w   = (const float*)d_in[2];
    const float* C_w   = (const float*)d_in[3];
    const float* Dp    = (const float*)d_in[4];
    const float* gamma = (const float*)d_in[5];
    const float* beta  = (const float*)d_in[6];
    float* out = (float*)d_out;

    float* bx = (float*)d_ws;                       // ROWS*16 floats (512 KB)
    float* kb = bx + (size_t)ROWS * D_STATE;        // WIN*16 floats (4 KB)

    k_proj<<<ROWS / K1_ROWS + D_STATE, 256, 0, stream>>>(x, B_w, A_log, bx, kb);
    k_tail<<<ROWS / KO_ROWS,           256, 0, stream>>>(x, bx, kb, C_w, Dp, gamma, beta, out);
}